// Round 14
// baseline (70.488 us; speedup 1.0000x reference)
//
#include <hip/hip_runtime.h>

#define B_   8
#define K_   256
#define C_   8
#define PS   64
#define H_   512
#define W_   512
#define TH   32
#define TW   32

// Single fused kernel (R13 body + in-kernel coord decode).
//  - int64/int32 coord-layout detection: each wave scans the 512 odd int32
//    words in raw[0..1024) (in-range under BOTH layouts; L2-hot after the
//    first block). All-zero <=> int64 little-endian (hi words of small
//    non-negative coords). Wave-level __any gives the same verdict in every
//    wave -> block-uniform, no barrier, no pre-kernel (R13 spent a serial
//    1-block decode launch ~3-5us before the grid could start).
//  - XCD-locality swizzle (R12) + tx-innermost work order (R13) + nontemporal
//    output stores (R13). Register-accumulate gather, clamped in-window
//    addresses masked by unclamped coords, no LDS accumulator, no atomics.
__global__ __launch_bounds__(256)
void gather_kernel(const float* __restrict__ logits,
                   const int* __restrict__ raw,
                   float* __restrict__ out) {
    const int wgid = blockIdx.x;
    const int w    = (wgid & 7) * 1024 + (wgid >> 3);  // XCD-contiguous work id
    const int tx   = w & 15;
    const int ty   = (w >> 4) & 15;
    const int cp   = (w >> 8) & 3;     // channels {2cp, 2cp+1}
    const int b    = w >> 10;

    const int ty0 = ty * TH;
    const int tx0 = tx * TW;
    const int tid = threadIdx.x;
    const int lane = tid & 63;

    __shared__ int s_rc[K_];    // packed (r<<16)|c, compacted in k-order
    __shared__ int s_kk[K_];    // accepted patch index
    __shared__ unsigned long long s_mask[4];

    // --- Phase 0: coord-layout detection (wave-redundant, block-uniform) ---
    int probe = 0;
#pragma unroll
    for (int j = 0; j < 8; ++j) probe |= raw[2 * (lane * 8 + j) + 1];
    const bool is64 = !__any(probe != 0);   // all odd words zero -> int64

    // --- Phase 1: ordered accept-list compaction (one coord per thread) ---
    {
        int2 cc;
        if (is64) {
            const int4 q = ((const int4*)raw)[b * K_ + tid];  // two int64s
            cc = make_int2(q.x, q.z);                         // lo words
        } else {
            cc = ((const int2*)raw)[b * K_ + tid];
        }
        bool hit = (cc.x < ty0 + TH) && (cc.x + PS > ty0) &&
                   (cc.y < tx0 + TW) && (cc.y + PS > tx0);
        unsigned long long m = __ballot(hit);
        const int wid = tid >> 6;
        if (lane == 0) s_mask[wid] = m;
        __syncthreads();
        int base = 0;
        for (int w2 = 0; w2 < wid; ++w2) base += __popcll(s_mask[w2]);
        if (hit) {
            int pos = base + __popcll(m & ((1ull << lane) - 1ull));
            s_rc[pos] = (cc.x << 16) | cc.y;
            s_kk[pos] = tid;
        }
    }
    int nacc = 0;
    for (int w2 = 0; w2 < 4; ++w2) nacc += __popcll(s_mask[w2]);
    __syncthreads();

    // --- Phase 2: register-accumulate gather, 2 channels ---
    float acc0[4], acc1[4], cnt[4];
#pragma unroll
    for (int j = 0; j < 4; ++j) { acc0[j] = acc1[j] = cnt[j] = 0.0f; }

    const int x  = tx0 + (tid & 31);   // owned column
    const int y0 = ty0 + (tid >> 5);   // owned rows: y0 + {0,8,16,24}

#pragma unroll 2
    for (int t = 0; t < nacc; ++t) {
        const int rcp = __builtin_amdgcn_readfirstlane(s_rc[t]);
        const int kk  = __builtin_amdgcn_readfirstlane(s_kk[t]);
        const int r = rcp >> 16, c = rcp & 0xffff;
        const float* __restrict__ pbase =
            logits + (((size_t)(b * K_ + kk)) << 15) + ((size_t)(2 * cp) << 12);

        // Valid overlap window in patch coords (non-empty by construction).
        const int pxlo = max(0, tx0 - c);
        const int pxhi = min(PS - 1, tx0 + TW - 1 - c);
        const int pylo = max(0, ty0 - r);
        const int pyhi = min(PS - 1, ty0 + TH - 1 - r);

        const int  px  = x - c;
        const int  pxc = min(max(px, pxlo), pxhi);   // in-window (in-bounds)
        const bool okx = (px == pxc);

        float f[4];
        int   off[4];
#pragma unroll
        for (int j = 0; j < 4; ++j) {
            const int py  = y0 + j * 8 - r;
            const int pyc = min(max(py, pylo), pyhi);
            f[j]   = (okx && (py == pyc)) ? 1.0f : 0.0f;
            off[j] = (pyc << 6) + pxc;               // inside window, fetched anyway
        }

        float v0[4], v1[4];
#pragma unroll
        for (int j = 0; j < 4; ++j) v0[j] = pbase[off[j]];
#pragma unroll
        for (int j = 0; j < 4; ++j) v1[j] = pbase[4096 + off[j]];

#pragma unroll
        for (int j = 0; j < 4; ++j) {
            cnt[j] += f[j];
            acc0[j] = fmaf(v0[j], f[j], acc0[j]);
            acc1[j] = fmaf(v1[j], f[j], acc1[j]);
        }
    }

    // --- Phase 3: fused finalize + nontemporal store (written exactly once) ---
#pragma unroll
    for (int j = 0; j < 4; ++j) {
        const int y = y0 + j * 8;
        const bool covered = cnt[j] > 1e-6f;
        const float inv = 1.0f / fmaxf(cnt[j], 1e-6f);
        const size_t o0 = (((size_t)(b * C_ + 2 * cp)) << 18) + y * W_ + x;
        __builtin_nontemporal_store(covered ? acc0[j] * inv : -10.0f, out + o0);
        __builtin_nontemporal_store(covered ? acc1[j] * inv : -10.0f,
                                    out + o0 + (1ull << 18));
    }
}

extern "C" void kernel_launch(void* const* d_in, const int* in_sizes, int n_in,
                              void* d_out, int out_size, void* d_ws, size_t ws_size,
                              hipStream_t stream) {
    const float* logits = (const float*)d_in[0];
    const int* raw = (const int*)d_in[1];
    float* out = (float*)d_out;

    gather_kernel<<<8192, 256, 0, stream>>>(logits, raw, out);
}

// Round 15
// 57.887 us; speedup vs baseline: 1.2177x; 1.2177x over previous
//
#include <hip/hip_runtime.h>

#define B_   8
#define K_   256
#define C_   8
#define PS   64
#define H_   512
#define W_   512
#define TH   32
#define TW   32

// Single fused kernel (R13 body + CHEAP in-kernel coord decode).
//  - Layout probe is ONE load per lane (odd words raw[1,3,..,127]; in-range
//    under both layouts). All-zero <=> int64 (hi words of 64 small coords are
//    all zero; int32 layout would need 64 consecutive zero coords -> never for
//    this data). One latency round (~0.1us/block) vs R14's 8 dependent rounds
//    (~5us total regression) vs R13's serial decode pre-kernel (~4us launch).
//  - XCD-locality swizzle (R12) + tx-innermost work order (R13) + nontemporal
//    output stores (R13). Register-accumulate gather, clamped in-window
//    addresses masked by unclamped coords, no LDS accumulator, no atomics.
__global__ __launch_bounds__(256)
void gather_kernel(const float* __restrict__ logits,
                   const int* __restrict__ raw,
                   float* __restrict__ out) {
    const int wgid = blockIdx.x;
    const int w    = (wgid & 7) * 1024 + (wgid >> 3);  // XCD-contiguous work id
    const int tx   = w & 15;
    const int ty   = (w >> 4) & 15;
    const int cp   = (w >> 8) & 3;     // channels {2cp, 2cp+1}
    const int b    = w >> 10;

    const int ty0 = ty * TH;
    const int tx0 = tx * TW;
    const int tid = threadIdx.x;
    const int lane = tid & 63;

    __shared__ int s_rc[K_];    // packed (r<<16)|c, compacted in k-order
    __shared__ int s_kk[K_];    // accepted patch index
    __shared__ unsigned long long s_mask[4];

    // --- Phase 0: coord-layout probe (one load per lane, block-uniform) ---
    const bool is64 = !__any(raw[2 * lane + 1] != 0);

    // --- Phase 1: ordered accept-list compaction (one coord per thread) ---
    {
        int2 cc;
        if (is64) {
            const int4 q = ((const int4*)raw)[b * K_ + tid];  // two int64s
            cc = make_int2(q.x, q.z);                         // lo words
        } else {
            cc = ((const int2*)raw)[b * K_ + tid];
        }
        bool hit = (cc.x < ty0 + TH) && (cc.x + PS > ty0) &&
                   (cc.y < tx0 + TW) && (cc.y + PS > tx0);
        unsigned long long m = __ballot(hit);
        const int wid = tid >> 6;
        if (lane == 0) s_mask[wid] = m;
        __syncthreads();
        int base = 0;
        for (int w2 = 0; w2 < wid; ++w2) base += __popcll(s_mask[w2]);
        if (hit) {
            int pos = base + __popcll(m & ((1ull << lane) - 1ull));
            s_rc[pos] = (cc.x << 16) | cc.y;
            s_kk[pos] = tid;
        }
    }
    int nacc = 0;
    for (int w2 = 0; w2 < 4; ++w2) nacc += __popcll(s_mask[w2]);
    __syncthreads();

    // --- Phase 2: register-accumulate gather, 2 channels ---
    float acc0[4], acc1[4], cnt[4];
#pragma unroll
    for (int j = 0; j < 4; ++j) { acc0[j] = acc1[j] = cnt[j] = 0.0f; }

    const int x  = tx0 + (tid & 31);   // owned column
    const int y0 = ty0 + (tid >> 5);   // owned rows: y0 + {0,8,16,24}

#pragma unroll 2
    for (int t = 0; t < nacc; ++t) {
        const int rcp = __builtin_amdgcn_readfirstlane(s_rc[t]);
        const int kk  = __builtin_amdgcn_readfirstlane(s_kk[t]);
        const int r = rcp >> 16, c = rcp & 0xffff;
        const float* __restrict__ pbase =
            logits + (((size_t)(b * K_ + kk)) << 15) + ((size_t)(2 * cp) << 12);

        // Valid overlap window in patch coords (non-empty by construction).
        const int pxlo = max(0, tx0 - c);
        const int pxhi = min(PS - 1, tx0 + TW - 1 - c);
        const int pylo = max(0, ty0 - r);
        const int pyhi = min(PS - 1, ty0 + TH - 1 - r);

        const int  px  = x - c;
        const int  pxc = min(max(px, pxlo), pxhi);   // in-window (in-bounds)
        const bool okx = (px == pxc);

        float f[4];
        int   off[4];
#pragma unroll
        for (int j = 0; j < 4; ++j) {
            const int py  = y0 + j * 8 - r;
            const int pyc = min(max(py, pylo), pyhi);
            f[j]   = (okx && (py == pyc)) ? 1.0f : 0.0f;
            off[j] = (pyc << 6) + pxc;               // inside window, fetched anyway
        }

        float v0[4], v1[4];
#pragma unroll
        for (int j = 0; j < 4; ++j) v0[j] = pbase[off[j]];
#pragma unroll
        for (int j = 0; j < 4; ++j) v1[j] = pbase[4096 + off[j]];

#pragma unroll
        for (int j = 0; j < 4; ++j) {
            cnt[j] += f[j];
            acc0[j] = fmaf(v0[j], f[j], acc0[j]);
            acc1[j] = fmaf(v1[j], f[j], acc1[j]);
        }
    }

    // --- Phase 3: fused finalize + nontemporal store (written exactly once) ---
#pragma unroll
    for (int j = 0; j < 4; ++j) {
        const int y = y0 + j * 8;
        const bool covered = cnt[j] > 1e-6f;
        const float inv = 1.0f / fmaxf(cnt[j], 1e-6f);
        const size_t o0 = (((size_t)(b * C_ + 2 * cp)) << 18) + y * W_ + x;
        __builtin_nontemporal_store(covered ? acc0[j] * inv : -10.0f, out + o0);
        __builtin_nontemporal_store(covered ? acc1[j] * inv : -10.0f,
                                    out + o0 + (1ull << 18));
    }
}

extern "C" void kernel_launch(void* const* d_in, const int* in_sizes, int n_in,
                              void* d_out, int out_size, void* d_ws, size_t ws_size,
                              hipStream_t stream) {
    const float* logits = (const float*)d_in[0];
    const int* raw = (const int*)d_in[1];
    float* out = (float*)d_out;

    gather_kernel<<<8192, 256, 0, stream>>>(logits, raw, out);
}